// Round 4
// baseline (2247.808 us; speedup 1.0000x reference)
//
#include <hip/hip_runtime.h>
#include <stdint.h>

typedef unsigned int u32;
typedef unsigned long long u64;

// ---------------- marching-tets tables ----------------
__device__ __constant__ int c_TRI[16][6] = {
 {-1,-1,-1,-1,-1,-1},{1,0,2,-1,-1,-1},{4,0,3,-1,-1,-1},{1,4,2,1,3,4},
 {3,1,5,-1,-1,-1},{2,3,0,2,5,3},{1,4,0,1,5,4},{4,2,5,-1,-1,-1},
 {4,5,2,-1,-1,-1},{4,1,0,4,5,1},{3,2,0,3,5,2},{1,3,5,-1,-1,-1},
 {4,1,2,4,3,1},{3,0,4,-1,-1,-1},{2,0,1,-1,-1,-1},{-1,-1,-1,-1,-1,-1}};
__device__ __constant__ int c_NTRI[16] = {0,1,1,2,1,2,2,1,1,2,2,1,2,1,1,0};
__device__ __constant__ int c_NTET[16] = {0,1,1,3,1,3,3,3,1,3,3,3,3,3,3,1};
__device__ __constant__ int c_TET[16][12] = {
 {-1,-1,-1,-1,-1,-1,-1,-1,-1,-1,-1,-1},{0,4,5,6,-1,-1,-1,-1,-1,-1,-1,-1},
 {1,4,8,7,-1,-1,-1,-1,-1,-1,-1,-1},{7,1,8,6,5,1,7,6,5,0,1,6},
 {2,5,7,9,-1,-1,-1,-1,-1,-1,-1,-1},{4,0,6,7,9,0,7,6,7,0,9,2},
 {4,1,9,8,5,1,9,4,5,1,2,9},{6,0,1,2,8,6,1,2,9,6,8,2},
 {3,6,9,8,-1,-1,-1,-1,-1,-1,-1,-1},{5,0,4,8,5,0,8,3,5,8,9,3},
 {1,4,7,3,4,7,6,3,9,6,7,3},{0,1,5,3,5,1,9,3,5,1,7,9},
 {5,2,3,7,3,6,5,8,3,5,7,8},{0,4,7,8,0,3,8,7,0,3,7,2},
 {4,1,2,3,4,3,2,5,4,3,5,6},{0,1,2,3,-1,-1,-1,-1,-1,-1,-1,-1}};
__device__ __constant__ int c_EV[12] = {0,1,0,2,0,3,1,2,1,3,2,3};

// header slots: 0:V 1:E 2:U 3:Ecross 4:Nf1 5:Nf2 6:Nt1 7:Nt3 8:Ninner 9:NU 10:R
//               16..24: slice boundaries (equal-mass octiles of mn histogram)
#define GSLOOP(i,n) for (long long i = (long long)blockIdx.x*blockDim.x + threadIdx.x; \
                         i < (long long)(n); i += (long long)gridDim.x*blockDim.x)

// ---------------- generic exclusive scan (u32, in place) ----------------
__global__ __launch_bounds__(256) void k_scan1(u32* data, u32* partials,
                                               const u32* hdr, int nslot, u32 nmax) {
  __shared__ u32 lds[2048];
  __shared__ u32 tsum[256];
  u32 n = (nslot >= 0) ? hdr[nslot] : nmax;
  u32 base = blockIdx.x * 2048u;
  for (int k = threadIdx.x; k < 2048; k += 256) {
    u32 i = base + (u32)k;
    lds[k] = (i < n) ? data[i] : 0u;
  }
  __syncthreads();
  u32 o = threadIdx.x * 8u;
  u32 run = 0; u32 loc[8];
  #pragma unroll
  for (int j = 0; j < 8; j++) { loc[j] = run; run += lds[o + j]; }
  tsum[threadIdx.x] = run;
  __syncthreads();
  for (int off = 1; off < 256; off <<= 1) {
    u32 v = tsum[threadIdx.x];
    u32 add = (threadIdx.x >= (u32)off) ? tsum[threadIdx.x - off] : 0u;
    __syncthreads();
    tsum[threadIdx.x] = v + add;
    __syncthreads();
  }
  u32 texc = (threadIdx.x == 0) ? 0u : tsum[threadIdx.x - 1];
  #pragma unroll
  for (int j = 0; j < 8; j++) {
    u32 i = base + o + (u32)j;
    if (i < n) data[i] = texc + loc[j];
  }
  if (threadIdx.x == 0) partials[blockIdx.x] = tsum[255];
}

__global__ __launch_bounds__(1024) void k_scan2(u32* partials, const u32* hdr, int nslot,
                                                u32 nmax, u32* hdrw, int tslot) {
  __shared__ u32 lds[8192];
  __shared__ u32 tsum[1024];
  u32 n = (nslot >= 0) ? hdr[nslot] : nmax;
  u32 nb = (n + 2047u) / 2048u;
  for (int k = threadIdx.x; k < 8192; k += 1024) lds[k] = ((u32)k < nb) ? partials[k] : 0u;
  __syncthreads();
  u32 o = threadIdx.x * 8u;
  u32 run = 0; u32 loc[8];
  #pragma unroll
  for (int j = 0; j < 8; j++) { loc[j] = run; run += lds[o + j]; }
  tsum[threadIdx.x] = run;
  __syncthreads();
  for (int off = 1; off < 1024; off <<= 1) {
    u32 v = tsum[threadIdx.x];
    u32 add = (threadIdx.x >= (u32)off) ? tsum[threadIdx.x - off] : 0u;
    __syncthreads();
    tsum[threadIdx.x] = v + add;
    __syncthreads();
  }
  u32 texc = (threadIdx.x == 0) ? 0u : tsum[threadIdx.x - 1];
  #pragma unroll
  for (int j = 0; j < 8; j++) { u32 k = o + (u32)j; if (k < nb) partials[k] = texc + loc[j]; }
  if (threadIdx.x == 0 && tslot >= 0) hdrw[tslot] = tsum[1023];
}

__global__ __launch_bounds__(256) void k_scan3(u32* data, const u32* partials,
                                               const u32* hdr, int nslot, u32 nmax) {
  u32 n = (nslot >= 0) ? hdr[nslot] : nmax;
  u32 base = blockIdx.x * 2048u;
  if (base >= n || blockIdx.x == 0) return;
  u32 add = partials[blockIdx.x];
  if (add == 0) return;
  for (int k = threadIdx.x; k < 2048; k += 256) {
    u32 i = base + (u32)k;
    if (i < n) data[i] += add;
  }
}

// ---------------- pipeline kernels ----------------
__global__ void k_zero32(u32* p, long long n) { GSLOOP(i, n) p[i] = 0u; }
__global__ void k_zero_hdr(u32* p, const u32* hdr, int slot, u32 extra) {
  long long n = (long long)hdr[slot] + extra;
  GSLOOP(i, n) p[i] = 0u;
}
__global__ void k_copy32(const u32* s, u32* d, long long n) { GSLOOP(i, n) d[i] = s[i]; }

__global__ void k_occ(const float* sdf, const float* th, unsigned char* occ, int N) {
  float t = th[0];
  GSLOOP(i, N) { float s = sdf[i]; occ[i] = (s > 0.f && s <= t) ? 1 : 0; }
}

__global__ void k_ti(const int* tet, const unsigned char* occ, unsigned char* ti,
                     u32* S1, long long F) {
  GSLOOP(f, F) {
    int v0 = tet[4*f], v1 = tet[4*f+1], v2 = tet[4*f+2], v3 = tet[4*f+3];
    int b = (int)occ[v0] | ((int)occ[v1] << 1) | ((int)occ[v2] << 2) | ((int)occ[v3] << 3);
    ti[f] = (unsigned char)b;
    S1[f] = (b != 0 && b != 15) ? 1u : 0u;
  }
}

__global__ void k_compact_valid(const u32* S1, const unsigned char* ti, u32* vidx, long long F) {
  GSLOOP(f, F) { int b = ti[f]; if (b != 0 && b != 15) vidx[S1[f]] = (u32)f; }
}

__global__ void k_hist(const int* tet, const u32* vidx, const u32* hdr, u32* hist) {
  u32 V = hdr[0];
  GSLOOP(t, V) {
    long long f = vidx[t];
    int v[4] = { tet[4*f], tet[4*f+1], tet[4*f+2], tet[4*f+3] };
    #pragma unroll
    for (int e = 0; e < 6; e++) {
      int a = v[c_EV[2*e]], b = v[c_EV[2*e+1]];
      int mn = a < b ? a : b;
      atomicAdd(&hist[mn], 1u);
    }
  }
}

// device-computed equal-mass slice boundaries over the mn histogram (off = scanned hist)
__global__ void k_bnd(const u32* off, u32* hdr, int N) {
  int g = threadIdx.x;
  if (g > 8) return;
  if (g == 8) { hdr[16 + 8] = (u32)N; return; }
  u64 target = ((u64)hdr[1] * (u64)g) / 8ull;
  u32 lo = 0, hi = (u32)N;
  while (lo < hi) { u32 m = (lo + hi) >> 1; if ((u64)off[m] < target) lo = m + 1; else hi = m; }
  hdr[16 + g] = lo;
}

// sliced scatter: blocks with bid%8==g handle slice g only -> per-XCD-L2-resident writes
__global__ void k_scatter8(const int* tet, const u32* vidx, const u32* hdr,
                           u32* cursor, u32* bmx) {
  int g = blockIdx.x & 7;
  u32 lo = hdr[16 + g], hi = hdr[16 + g + 1];
  u32 V = hdr[0];
  for (long long t = (long long)(blockIdx.x >> 3) * blockDim.x + threadIdx.x; t < (long long)V;
       t += (long long)(gridDim.x >> 3) * blockDim.x) {
    long long f = vidx[t];
    int v[4] = { tet[4*f], tet[4*f+1], tet[4*f+2], tet[4*f+3] };
    #pragma unroll
    for (int e = 0; e < 6; e++) {
      int a = v[c_EV[2*e]], b = v[c_EV[2*e+1]];
      int mn = a < b ? a : b, mx = a < b ? b : a;
      if ((u32)mn >= lo && (u32)mn < hi) {
        u32 p = atomicAdd(&cursor[mn], 1u);
        bmx[p] = (u32)mx;
      }
    }
  }
}

template<int KMAX>
__device__ __forceinline__ void bitonic_lane(u32& val, int lane) {
  #pragma unroll
  for (int k = 2; k <= KMAX; k <<= 1) {
    #pragma unroll
    for (int j = k >> 1; j > 0; j >>= 1) {
      u32 other = __shfl_xor(val, j, 64);
      bool keepmin = ((lane & k) == 0) == ((lane & j) == 0);
      bool smaller = val < other;
      val = (keepmin == smaller) ? val : other;
    }
  }
}

// one wave64 per bucket: sort u32 mx values; also emit unique-flags into Fl
__global__ __launch_bounds__(256) void k_bsort(const u32* off, u32* bmx, u32* Fl, int N) {
  int lane = threadIdx.x & 63;
  long long wid = ((long long)blockIdx.x * blockDim.x + threadIdx.x) >> 6;
  long long nw  = ((long long)gridDim.x * blockDim.x) >> 6;
  for (long long v = wid; v < N; v += nw) {
    u32 s = off[v], e = off[v + 1];
    u32 cnt = e - s;
    if (cnt == 0) continue;
    if (cnt == 1) { if (lane == 0) Fl[s] = 1u; continue; }
    if (cnt <= 64) {
      u32 val = (lane < (int)cnt) ? bmx[s + lane] : 0xffffffffu;
      if      (cnt <= 2)  bitonic_lane<2>(val, lane);
      else if (cnt <= 4)  bitonic_lane<4>(val, lane);
      else if (cnt <= 8)  bitonic_lane<8>(val, lane);
      else if (cnt <= 16) bitonic_lane<16>(val, lane);
      else if (cnt <= 32) bitonic_lane<32>(val, lane);
      else                bitonic_lane<64>(val, lane);
      u32 prev = __shfl_up(val, 1, 64);
      if (lane < (int)cnt) {
        bmx[s + lane] = val;
        Fl[s + lane] = (lane == 0 || val != prev) ? 1u : 0u;
      }
    } else if (cnt <= 256) {
      u32 vals[4];
      #pragma unroll
      for (int r = 0; r < 4; r++) {
        int idx = r * 64 + lane;
        vals[r] = (idx < (int)cnt) ? bmx[s + idx] : 0xffffffffu;
      }
      #pragma unroll
      for (int k = 2; k <= 256; k <<= 1) {
        #pragma unroll
        for (int j = 128; j > 0; j >>= 1) {
          if (j >= k) continue;
          if (j >= 64) {
            int rj = j >> 6;
            #pragma unroll
            for (int r = 0; r < 4; r++) {
              int pr = r ^ rj;
              if (pr > r) {
                int i0 = r * 64 + lane;
                bool keepmin = ((i0 & k) == 0);
                u32 a = vals[r], b = vals[pr];
                u32 mn = a < b ? a : b, mx = a < b ? b : a;
                vals[r]  = keepmin ? mn : mx;
                vals[pr] = keepmin ? mx : mn;
              }
            }
          } else {
            #pragma unroll
            for (int r = 0; r < 4; r++) {
              int i0 = r * 64 + lane;
              u32 other = __shfl_xor(vals[r], j, 64);
              bool keepmin = ((i0 & k) == 0) == ((i0 & j) == 0);
              bool smaller = vals[r] < other;
              vals[r] = (keepmin == smaller) ? vals[r] : other;
            }
          }
        }
      }
      #pragma unroll
      for (int r = 0; r < 4; r++) {
        u32 pv = __shfl_up(vals[r], 1, 64);
        u32 lastprev = (r > 0) ? __shfl(vals[r - 1], 63, 64) : 0u;
        int idx = r * 64 + lane;
        u32 prev = (lane == 0) ? lastprev : pv;
        if (idx < (int)cnt) {
          bmx[s + idx] = vals[r];
          Fl[s + idx] = (idx == 0 || vals[r] != prev) ? 1u : 0u;
        }
      }
    } else if (lane == 0) {
      for (u32 i = s + 1; i < e; i++) {
        u32 kk = bmx[i]; u32 j = i;
        while (j > s && bmx[j - 1] > kk) { bmx[j] = bmx[j - 1]; j--; }
        bmx[j] = kk;
      }
      for (u32 j = s; j < e; j++) Fl[j] = (j == s || bmx[j] != bmx[j - 1]) ? 1u : 0u;
    }
  }
}

// wave per bucket: compact unique (mn,mx) pairs into uk using scanned ranks Rk
__global__ __launch_bounds__(256) void k_ucompact(const u32* off, const u32* bmx,
                                                  const u32* Rk, u64* uk, int N) {
  int lane = threadIdx.x & 63;
  long long wid = ((long long)blockIdx.x * blockDim.x + threadIdx.x) >> 6;
  long long nw  = ((long long)gridDim.x * blockDim.x) >> 6;
  for (long long v = wid; v < N; v += nw) {
    u32 s = off[v], e = off[v + 1];
    for (u32 j = s + (u32)lane; j < e; j += 64) {
      u32 mx = bmx[j];
      bool fl = (j == s) || (mx != bmx[j - 1]);
      if (fl) uk[Rk[j]] = ((u64)v << 32) | (u64)mx;
    }
  }
}

__global__ void k_cflag(const u64* uk, const unsigned char* occ, u32* Cf, const u32* hdr) {
  u32 U = hdr[2];
  GSLOOP(u, U) {
    u64 k = uk[u]; int a = (int)(k >> 32), b = (int)(k & 0xffffffffu);
    Cf[u] = (((int)occ[a] + (int)occ[b]) == 1) ? 1u : 0u;
  }
}

// in-place: Cf holds scanned crossing-flags; overwrite with mapping (or -1)
__global__ void k_mapping(const u64* uk, const unsigned char* occ, int* Cf,
                          u32* hdr, int N) {
  if (blockIdx.x == 0 && threadIdx.x == 0) hdr[10] = (u32)N + hdr[3];
  u32 U = hdr[2];
  GSLOOP(u, U) {
    u64 k = uk[u]; int a = (int)(k >> 32), b = (int)(k & 0xffffffffu);
    bool c = (((int)occ[a] + (int)occ[b]) == 1);
    Cf[u] = c ? Cf[u] : -1;
  }
}

// per-occurrence idx_map via bucket-local binary search over unique edges
__global__ void k_idxmap(const int* tet, const u32* vidx, const u32* off,
                         const u32* Rk, const u64* uk, const int* mapping,
                         int* idx_map, const u32* hdr) {
  u32 V = hdr[0], E = hdr[1], U = hdr[2];
  GSLOOP(t, V) {
    long long f = vidx[t];
    int v[4] = { tet[4*f], tet[4*f+1], tet[4*f+2], tet[4*f+3] };
    #pragma unroll
    for (int e = 0; e < 6; e++) {
      int a = v[c_EV[2*e]], b = v[c_EV[2*e+1]];
      int mn = a < b ? a : b, mx = a < b ? b : a;
      u32 s = off[mn], s2 = off[mn + 1];
      u32 lo = Rk[s];
      u32 hi = (s2 < E) ? Rk[s2] : U;
      while (lo < hi) {
        u32 m = (lo + hi) >> 1;
        if ((u32)(uk[m] & 0xffffffffu) < (u32)mx) lo = m + 1; else hi = m;
      }
      idx_map[6 * t + e] = mapping[lo];
    }
  }
}

__global__ void k_interp(const u64* uk, const int* mapping, const float* pos,
                         const float* sdf, const float* th, float* out, const u32* hdr) {
  u32 U = hdr[2];
  float t = th[0];
  GSLOOP(u, U) {
    int m = mapping[u]; if (m < 0) continue;
    u64 k = uk[u]; int a = (int)(k >> 32), b = (int)(k & 0xffffffffu);
    float s0 = sdf[a], s1 = sdf[b];
    if (s0 > 0.f && s1 > 0.f) { s0 = __fsub_rn(s0, t); s1 = __fsub_rn(s1, t); }
    float denom = __fadd_rn(s0, -s1);
    float w0 = __fdiv_rn(-s1, denom);
    float w1 = __fdiv_rn(s0, denom);
    long long base = 3ll * m;
    #pragma unroll
    for (int kk = 0; kk < 3; kk++)
      out[base + kk] = __fadd_rn(__fmul_rn(pos[3ll*a + kk], w0), __fmul_rn(pos[3ll*b + kk], w1));
  }
}

__global__ void k_pred_faces(const unsigned char* ti, u32* S1, u32* S2, long long F) {
  GSLOOP(f, F) {
    int b = ti[f]; bool valid = (b != 0 && b != 15); int nt = c_NTRI[b];
    S1[f] = (valid && nt == 1) ? 1u : 0u;
    S2[f] = (valid && nt == 2) ? 1u : 0u;
  }
}

__global__ void k_faces(const u32* vidx, const unsigned char* ti, const int* idx_map,
                        const u32* S1, const u32* S2, float* out, const u32* hdr) {
  u32 V = hdr[0];
  unsigned long long fo = 3ull * hdr[3];
  u32 Nf1 = hdr[4];
  GSLOOP(t, V) {
    u32 f = vidx[t]; int b = ti[f]; int nt = c_NTRI[b];
    if (nt == 1) {
      unsigned long long base = fo + 3ull * S1[f];
      for (int k = 0; k < 3; k++) out[base + k] = (float)idx_map[6*t + c_TRI[b][k]];
    } else {
      unsigned long long base = fo + 3ull * Nf1 + 6ull * S2[f];
      for (int k = 0; k < 6; k++) out[base + k] = (float)idx_map[6*t + c_TRI[b][k]];
    }
  }
}

__global__ void k_pred_tets(const unsigned char* ti, u32* S1, u32* S2, u32* S3, long long F) {
  GSLOOP(f, F) {
    int b = ti[f]; bool valid = (b != 0 && b != 15); int ntt = c_NTET[b];
    S1[f] = (valid && ntt == 1) ? 1u : 0u;
    S2[f] = (valid && ntt == 3) ? 1u : 0u;
    S3[f] = (b == 15) ? 1u : 0u;
  }
}

__global__ void k_tets_valid(const int* tet, const u32* vidx, const unsigned char* ti,
                             const int* idx_map, const u32* S1, const u32* S2,
                             int* at, const u32* hdr, int N) {
  u32 V = hdr[0]; u32 Nt1 = hdr[6];
  GSLOOP(t, V) {
    u32 f = vidx[t]; int b = ti[f];
    int tv[10];
    for (int k = 0; k < 4; k++) tv[k] = tet[4ll*f + k];
    for (int j = 0; j < 6; j++) tv[4 + j] = idx_map[6*t + j] + N;
    int ntt = c_NTET[b];
    if (ntt == 1) {
      long long base = 4ll * S1[f];
      for (int k = 0; k < 4; k++) at[base + k] = tv[c_TET[b][k]];
    } else {
      long long base = 4ll * Nt1 + 12ll * S2[f];
      for (int k = 0; k < 12; k++) at[base + k] = tv[c_TET[b][k]];
    }
  }
}

__global__ void k_tets_inner(const int* tet, const unsigned char* ti, const u32* S3,
                             int* at, const u32* hdr, long long F) {
  long long base0 = 4ll * hdr[6] + 12ll * hdr[7];
  GSLOOP(f, F) {
    if (ti[f] == 15) {
      long long base = base0 + 4ll * S3[f];
      for (int k = 0; k < 4; k++) at[base + k] = tet[4*f + k];
    }
  }
}

__global__ void k_mark(const int* at, u32* Big, const u32* hdr) {
  long long NA = 4ll * hdr[6] + 12ll * hdr[7] + 4ll * hdr[8];
  GSLOOP(i, NA) Big[at[i]] = 1u;
}

__global__ void k_vtm(const u32* Big, const float* pos, float* out, const u32* hdr, int N) {
  u32 R = hdr[10], NU = hdr[9];
  unsigned long long vtm = 3ull * hdr[3] + 3ull * (hdr[4] + 2u * hdr[5]);
  GSLOOP(v, R) {
    u32 r = Big[v];
    u32 nx = (v + 1 < (long long)R) ? Big[v + 1] : NU;
    if (nx > r) {
      unsigned long long base = vtm + 3ull * r;
      if (v < N) { for (int k = 0; k < 3; k++) out[base + k] = pos[3*v + k]; }
      else { long long src = 3ll * (v - N); for (int k = 0; k < 3; k++) out[base + k] = out[src + k]; }
    }
  }
}

__global__ void k_tets_out(const int* at, const u32* Big, float* out, const u32* hdr) {
  long long NA = 4ll * hdr[6] + 12ll * hdr[7] + 4ll * hdr[8];
  unsigned long long toff = 3ull * hdr[3] + 3ull * (hdr[4] + 2u * hdr[5]) + 3ull * hdr[9];
  GSLOOP(i, NA) out[toff + i] = (float)Big[at[i]];
}

// ---------------- host ----------------
extern "C" void kernel_launch(void* const* d_in, const int* in_sizes, int n_in,
                              void* d_out, int out_size, void* d_ws, size_t ws_size,
                              hipStream_t stream) {
  const float* pos = (const float*)d_in[0];
  const float* sdf = (const float*)d_in[1];
  const int*   tet = (const int*)d_in[2];
  const float* th  = (const float*)d_in[3];
  float* out = (float*)d_out;

  const int N = in_sizes[1];
  const long long F = (long long)in_sizes[2] / 4;
  const long long MAXE = 6 * F;
  const long long RMAX = (long long)N + MAXE;
  (void)n_in; (void)out_size; (void)ws_size;

  char* w = (char*)d_ws;
  size_t off = 0;
  auto alloc = [&](size_t b) -> char* {
    char* p = w + off; off = (off + b + 255) & ~(size_t)255; return p;
  };
  u32* hdr            = (u32*)alloc(64 * 4);
  unsigned char* occ  = (unsigned char*)alloc((size_t)N);
  unsigned char* tiA  = (unsigned char*)alloc((size_t)F);
  u32* S1             = (u32*)alloc(4 * (size_t)F);
  u32* S2             = (u32*)alloc(4 * (size_t)F);
  u32* S3             = (u32*)alloc(4 * (size_t)F);
  u32* vidx           = (u32*)alloc(4 * (size_t)F);
  u32* hist           = (u32*)alloc(4 * ((size_t)N + 2));
  u32* cursor         = (u32*)alloc(4 * ((size_t)N + 2));
  // 96MB region: during edge phase = bmx(u32 MAXE) + Rk(u32 MAXE); later = at(int 12F)
  char* big_mem       = alloc(8 * (size_t)MAXE);
  u32* bmx = (u32*)big_mem;
  u32* Rk  = (u32*)(big_mem + 4 * (size_t)MAXE);
  int* at  = (int*)big_mem;
  u64* uk             = (u64*)alloc(8 * (size_t)MAXE);
  u32* Big            = (u32*)alloc(4 * ((size_t)RMAX + 2));
  int* mapping        = (int*)alloc(4 * (size_t)MAXE);
  int* idx_map        = (int*)alloc(4 * (size_t)MAXE);
  u32* partials       = (u32*)alloc(4 * 8192);

  const int GRID = 4096, BLK = 256;
  auto scan = [&](u32* data, int nslot, u32 nmax, int tslot) {
    int nb = (int)((nmax + 2047u) / 2048u);
    k_scan1<<<nb, 256, 0, stream>>>(data, partials, hdr, nslot, nmax);
    k_scan2<<<1, 1024, 0, stream>>>(partials, hdr, nslot, nmax, hdr, tslot);
    k_scan3<<<nb, 256, 0, stream>>>(data, partials, hdr, nslot, nmax);
  };

  k_zero32<<<1, 64, 0, stream>>>(hdr, 64);
  k_zero32<<<2048, BLK, 0, stream>>>(hist, (long long)N + 2);

  k_occ<<<GRID, BLK, 0, stream>>>(sdf, th, occ, N);
  k_ti<<<GRID, BLK, 0, stream>>>(tet, occ, tiA, S1, F);
  scan(S1, -1, (u32)F, 0);                                   // hdr[0] = V
  k_compact_valid<<<GRID, BLK, 0, stream>>>(S1, tiA, vidx, F);

  k_hist<<<GRID, BLK, 0, stream>>>(tet, vidx, hdr, hist);
  scan(hist, -1, (u32)(N + 1), 1);                           // hdr[1] = E = 6V; hist -> off
  k_bnd<<<1, 64, 0, stream>>>(hist, hdr, N);                 // hdr[16..24] = octile bounds
  k_copy32<<<GRID, BLK, 0, stream>>>(hist, cursor, (long long)N + 2);
  k_scatter8<<<GRID, BLK, 0, stream>>>(tet, vidx, hdr, cursor, bmx);
  k_bsort<<<GRID, BLK, 0, stream>>>(hist, bmx, Rk, N);       // sort buckets + flags into Rk

  scan(Rk, 1, (u32)MAXE, 2);                                 // hdr[2] = U; Rk = uniq ranks
  k_ucompact<<<GRID, BLK, 0, stream>>>(hist, bmx, Rk, uk, N);

  k_cflag<<<GRID, BLK, 0, stream>>>(uk, occ, (u32*)mapping, hdr);
  scan((u32*)mapping, 2, (u32)MAXE, 3);                      // hdr[3] = Ecross
  k_mapping<<<GRID, BLK, 0, stream>>>(uk, occ, mapping, hdr, N);
  k_idxmap<<<GRID, BLK, 0, stream>>>(tet, vidx, hist, Rk, uk, mapping, idx_map, hdr);

  k_interp<<<GRID, BLK, 0, stream>>>(uk, mapping, pos, sdf, th, out, hdr);

  k_pred_faces<<<GRID, BLK, 0, stream>>>(tiA, S1, S2, F);
  scan(S1, -1, (u32)F, 4);                                   // hdr[4] = Nf1
  scan(S2, -1, (u32)F, 5);                                   // hdr[5] = Nf2
  k_faces<<<GRID, BLK, 0, stream>>>(vidx, tiA, idx_map, S1, S2, out, hdr);

  k_pred_tets<<<GRID, BLK, 0, stream>>>(tiA, S1, S2, S3, F);
  scan(S1, -1, (u32)F, 6);                                   // hdr[6] = Nt1
  scan(S2, -1, (u32)F, 7);                                   // hdr[7] = Nt3
  scan(S3, -1, (u32)F, 8);                                   // hdr[8] = Ninner
  k_tets_valid<<<GRID, BLK, 0, stream>>>(tet, vidx, tiA, idx_map, S1, S2, at, hdr, N);
  k_tets_inner<<<GRID, BLK, 0, stream>>>(tet, tiA, S3, at, hdr, F);

  k_zero_hdr<<<GRID, BLK, 0, stream>>>(Big, hdr, 10, 2u);
  k_mark<<<GRID, BLK, 0, stream>>>(at, Big, hdr);
  scan(Big, 10, (u32)RMAX, 9);                               // hdr[9] = NU (hdr[10]=R set in k_mapping)
  k_vtm<<<GRID, BLK, 0, stream>>>(Big, pos, out, hdr, N);
  k_tets_out<<<GRID, BLK, 0, stream>>>(at, Big, out, hdr);
}

// Round 5
// 1622.012 us; speedup vs baseline: 1.3858x; 1.3858x over previous
//
#include <hip/hip_runtime.h>
#include <stdint.h>

typedef unsigned int u32;
typedef unsigned long long u64;

// ---------------- marching-tets tables ----------------
__device__ __constant__ int c_TRI[16][6] = {
 {-1,-1,-1,-1,-1,-1},{1,0,2,-1,-1,-1},{4,0,3,-1,-1,-1},{1,4,2,1,3,4},
 {3,1,5,-1,-1,-1},{2,3,0,2,5,3},{1,4,0,1,5,4},{4,2,5,-1,-1,-1},
 {4,5,2,-1,-1,-1},{4,1,0,4,5,1},{3,2,0,3,5,2},{1,3,5,-1,-1,-1},
 {4,1,2,4,3,1},{3,0,4,-1,-1,-1},{2,0,1,-1,-1,-1},{-1,-1,-1,-1,-1,-1}};
__device__ __constant__ int c_NTRI[16] = {0,1,1,2,1,2,2,1,1,2,2,1,2,1,1,0};
__device__ __constant__ int c_NTET[16] = {0,1,1,3,1,3,3,3,1,3,3,3,3,3,3,1};
__device__ __constant__ int c_TET[16][12] = {
 {-1,-1,-1,-1,-1,-1,-1,-1,-1,-1,-1,-1},{0,4,5,6,-1,-1,-1,-1,-1,-1,-1,-1},
 {1,4,8,7,-1,-1,-1,-1,-1,-1,-1,-1},{7,1,8,6,5,1,7,6,5,0,1,6},
 {2,5,7,9,-1,-1,-1,-1,-1,-1,-1,-1},{4,0,6,7,9,0,7,6,7,0,9,2},
 {4,1,9,8,5,1,9,4,5,1,2,9},{6,0,1,2,8,6,1,2,9,6,8,2},
 {3,6,9,8,-1,-1,-1,-1,-1,-1,-1,-1},{5,0,4,8,5,0,8,3,5,8,9,3},
 {1,4,7,3,4,7,6,3,9,6,7,3},{0,1,5,3,5,1,9,3,5,1,7,9},
 {5,2,3,7,3,6,5,8,3,5,7,8},{0,4,7,8,0,3,8,7,0,3,7,2},
 {4,1,2,3,4,3,2,5,4,3,5,6},{0,1,2,3,-1,-1,-1,-1,-1,-1,-1,-1}};
__device__ __constant__ int c_EV[12] = {0,1,0,2,0,3,1,2,1,3,2,3};

// header slots: 0:V 1:E 2:- 3:Ecross 4:Nf1 5:Nf2 6:Nt1 7:Nt3 8:Ninner 9:NU 10:R
//               16..24: slice boundaries (equal-mass octiles of mn histogram)
#define GSLOOP(i,n) for (long long i = (long long)blockIdx.x*blockDim.x + threadIdx.x; \
                         i < (long long)(n); i += (long long)gridDim.x*blockDim.x)

// ---------------- generic exclusive scan (u32, in place) ----------------
__global__ __launch_bounds__(256) void k_scan1(u32* data, u32* partials,
                                               const u32* hdr, int nslot, u32 nmax) {
  __shared__ u32 lds[2048];
  __shared__ u32 tsum[256];
  u32 n = (nslot >= 0) ? hdr[nslot] : nmax;
  u32 base = blockIdx.x * 2048u;
  for (int k = threadIdx.x; k < 2048; k += 256) {
    u32 i = base + (u32)k;
    lds[k] = (i < n) ? data[i] : 0u;
  }
  __syncthreads();
  u32 o = threadIdx.x * 8u;
  u32 run = 0; u32 loc[8];
  #pragma unroll
  for (int j = 0; j < 8; j++) { loc[j] = run; run += lds[o + j]; }
  tsum[threadIdx.x] = run;
  __syncthreads();
  for (int off = 1; off < 256; off <<= 1) {
    u32 v = tsum[threadIdx.x];
    u32 add = (threadIdx.x >= (u32)off) ? tsum[threadIdx.x - off] : 0u;
    __syncthreads();
    tsum[threadIdx.x] = v + add;
    __syncthreads();
  }
  u32 texc = (threadIdx.x == 0) ? 0u : tsum[threadIdx.x - 1];
  #pragma unroll
  for (int j = 0; j < 8; j++) {
    u32 i = base + o + (u32)j;
    if (i < n) data[i] = texc + loc[j];
  }
  if (threadIdx.x == 0) partials[blockIdx.x] = tsum[255];
}

__global__ __launch_bounds__(1024) void k_scan2(u32* partials, const u32* hdr, int nslot,
                                                u32 nmax, u32* hdrw, int tslot) {
  __shared__ u32 lds[8192];
  __shared__ u32 tsum[1024];
  u32 n = (nslot >= 0) ? hdr[nslot] : nmax;
  u32 nb = (n + 2047u) / 2048u;
  for (int k = threadIdx.x; k < 8192; k += 1024) lds[k] = ((u32)k < nb) ? partials[k] : 0u;
  __syncthreads();
  u32 o = threadIdx.x * 8u;
  u32 run = 0; u32 loc[8];
  #pragma unroll
  for (int j = 0; j < 8; j++) { loc[j] = run; run += lds[o + j]; }
  tsum[threadIdx.x] = run;
  __syncthreads();
  for (int off = 1; off < 1024; off <<= 1) {
    u32 v = tsum[threadIdx.x];
    u32 add = (threadIdx.x >= (u32)off) ? tsum[threadIdx.x - off] : 0u;
    __syncthreads();
    tsum[threadIdx.x] = v + add;
    __syncthreads();
  }
  u32 texc = (threadIdx.x == 0) ? 0u : tsum[threadIdx.x - 1];
  #pragma unroll
  for (int j = 0; j < 8; j++) { u32 k = o + (u32)j; if (k < nb) partials[k] = texc + loc[j]; }
  if (threadIdx.x == 0 && tslot >= 0) hdrw[tslot] = tsum[1023];
}

__global__ __launch_bounds__(256) void k_scan3(u32* data, const u32* partials,
                                               const u32* hdr, int nslot, u32 nmax) {
  u32 n = (nslot >= 0) ? hdr[nslot] : nmax;
  u32 base = blockIdx.x * 2048u;
  if (base >= n || blockIdx.x == 0) return;
  u32 add = partials[blockIdx.x];
  if (add == 0) return;
  for (int k = threadIdx.x; k < 2048; k += 256) {
    u32 i = base + (u32)k;
    if (i < n) data[i] += add;
  }
}

// ---------------- pipeline kernels ----------------
__global__ void k_zero32(u32* p, long long n) { GSLOOP(i, n) p[i] = 0u; }
__global__ void k_zero_hdr(u32* p, const u32* hdr, int slot, u32 extra) {
  long long n = (long long)hdr[slot] + extra;
  GSLOOP(i, n) p[i] = 0u;
}
__global__ void k_copy32(const u32* s, u32* d, long long n) { GSLOOP(i, n) d[i] = s[i]; }
__global__ void k_setr(u32* hdr, int N) { hdr[10] = (u32)N + hdr[3]; }

__global__ void k_occ(const float* sdf, const float* th, unsigned char* occ, int N) {
  float t = th[0];
  GSLOOP(i, N) { float s = sdf[i]; occ[i] = (s > 0.f && s <= t) ? 1 : 0; }
}

__global__ void k_ti(const int* tet, const unsigned char* occ, unsigned char* ti,
                     u32* S1, long long F) {
  GSLOOP(f, F) {
    int v0 = tet[4*f], v1 = tet[4*f+1], v2 = tet[4*f+2], v3 = tet[4*f+3];
    int b = (int)occ[v0] | ((int)occ[v1] << 1) | ((int)occ[v2] << 2) | ((int)occ[v3] << 3);
    ti[f] = (unsigned char)b;
    S1[f] = (b != 0 && b != 15) ? 1u : 0u;
  }
}

__global__ void k_compact_valid(const u32* S1, const unsigned char* ti, u32* vidx, long long F) {
  GSLOOP(f, F) { int b = ti[f]; if (b != 0 && b != 15) vidx[S1[f]] = (u32)f; }
}

__global__ void k_hist(const int* tet, const u32* vidx, const u32* hdr, u32* hist) {
  u32 V = hdr[0];
  GSLOOP(t, V) {
    long long f = vidx[t];
    int v[4] = { tet[4*f], tet[4*f+1], tet[4*f+2], tet[4*f+3] };
    #pragma unroll
    for (int e = 0; e < 6; e++) {
      int a = v[c_EV[2*e]], b = v[c_EV[2*e+1]];
      int mn = a < b ? a : b;
      atomicAdd(&hist[mn], 1u);
    }
  }
}

// device-computed equal-mass slice boundaries over the mn histogram (off = scanned hist)
__global__ void k_bnd(const u32* off, u32* hdr, int N) {
  int g = threadIdx.x;
  if (g > 8) return;
  if (g == 8) { hdr[16 + 8] = (u32)N; return; }
  u64 target = ((u64)hdr[1] * (u64)g) / 8ull;
  u32 lo = 0, hi = (u32)N;
  while (lo < hi) { u32 m = (lo + hi) >> 1; if ((u64)off[m] < target) lo = m + 1; else hi = m; }
  hdr[16 + g] = lo;
}

// sliced scatter: key = mn<<(SB+OB) | mx<<OB | occurrence
__global__ void k_scatter8(const int* tet, const u32* vidx, const u32* hdr,
                           u32* cursor, u64* keys, int SB, int OB) {
  int g = blockIdx.x & 7;
  u32 lo = hdr[16 + g], hi = hdr[16 + g + 1];
  u32 V = hdr[0];
  for (long long t = (long long)(blockIdx.x >> 3) * blockDim.x + threadIdx.x; t < (long long)V;
       t += (long long)(gridDim.x >> 3) * blockDim.x) {
    long long f = vidx[t];
    int v[4] = { tet[4*f], tet[4*f+1], tet[4*f+2], tet[4*f+3] };
    #pragma unroll
    for (int e = 0; e < 6; e++) {
      int a = v[c_EV[2*e]], b = v[c_EV[2*e+1]];
      int mn = a < b ? a : b, mx = a < b ? b : a;
      if ((u32)mn >= lo && (u32)mn < hi) {
        u32 p = atomicAdd(&cursor[mn], 1u);
        keys[p] = (((u64)(u32)mn << (SB + OB)) | ((u64)(u32)mx << OB)) | (u64)(6ull * t + e);
      }
    }
  }
}

template<int KMAX>
__device__ __forceinline__ void bitonic_lane(u64& val, int lane) {
  #pragma unroll
  for (int k = 2; k <= KMAX; k <<= 1) {
    #pragma unroll
    for (int j = k >> 1; j > 0; j >>= 1) {
      u64 other = __shfl_xor(val, j, 64);
      bool keepmin = ((lane & k) == 0) == ((lane & j) == 0);
      bool smaller = val < other;
      val = (keepmin == smaller) ? val : other;
    }
  }
}

// one wave64 per bucket: sort keys; emit crossing-unique flags cfe
// (bucket start is always a unique start since mn differs across buckets)
__global__ __launch_bounds__(256) void k_bsort(const u32* off, u64* keys, u32* cfe,
                                               const unsigned char* occm, int N,
                                               int SB, int OB) {
  int lane = threadIdx.x & 63;
  u64 smask = ((u64)1 << SB) - 1;
  long long wid = ((long long)blockIdx.x * blockDim.x + threadIdx.x) >> 6;
  long long nw  = ((long long)gridDim.x * blockDim.x) >> 6;
  for (long long v = wid; v < N; v += nw) {
    u32 s = off[v], e = off[v + 1];
    u32 cnt = e - s;
    if (cnt == 0) continue;
    int ov = (int)occm[v];
    if (cnt == 1) {
      if (lane == 0) {
        u32 mx = (u32)((keys[s] >> OB) & smask);
        cfe[s] = ((ov + (int)occm[mx]) == 1) ? 1u : 0u;
      }
      continue;
    }
    if (cnt <= 64) {
      u64 val = (lane < (int)cnt) ? keys[s + lane] : ~0ull;
      if      (cnt <= 2)  bitonic_lane<2>(val, lane);
      else if (cnt <= 4)  bitonic_lane<4>(val, lane);
      else if (cnt <= 8)  bitonic_lane<8>(val, lane);
      else if (cnt <= 16) bitonic_lane<16>(val, lane);
      else if (cnt <= 32) bitonic_lane<32>(val, lane);
      else                bitonic_lane<64>(val, lane);
      u64 prev = __shfl_up(val, 1, 64);
      if (lane < (int)cnt) {
        keys[s + lane] = val;
        bool flag = (lane == 0) || ((val >> OB) != (prev >> OB));
        u32 mx = (u32)((val >> OB) & smask);
        cfe[s + lane] = (flag && ((ov + (int)occm[mx]) == 1)) ? 1u : 0u;
      }
    } else if (cnt <= 256) {
      u64 vals[4];
      #pragma unroll
      for (int r = 0; r < 4; r++) {
        int idx = r * 64 + lane;
        vals[r] = (idx < (int)cnt) ? keys[s + idx] : ~0ull;
      }
      #pragma unroll
      for (int k = 2; k <= 256; k <<= 1) {
        #pragma unroll
        for (int j = 128; j > 0; j >>= 1) {
          if (j >= k) continue;
          if (j >= 64) {
            int rj = j >> 6;
            #pragma unroll
            for (int r = 0; r < 4; r++) {
              int pr = r ^ rj;
              if (pr > r) {
                int i0 = r * 64 + lane;
                bool keepmin = ((i0 & k) == 0);
                u64 a = vals[r], b = vals[pr];
                u64 mn = a < b ? a : b, mx = a < b ? b : a;
                vals[r]  = keepmin ? mn : mx;
                vals[pr] = keepmin ? mx : mn;
              }
            }
          } else {
            #pragma unroll
            for (int r = 0; r < 4; r++) {
              int i0 = r * 64 + lane;
              u64 other = __shfl_xor(vals[r], j, 64);
              bool keepmin = ((i0 & k) == 0) == ((i0 & j) == 0);
              bool smaller = vals[r] < other;
              vals[r] = (keepmin == smaller) ? vals[r] : other;
            }
          }
        }
      }
      #pragma unroll
      for (int r = 0; r < 4; r++) {
        u64 pv = __shfl_up(vals[r], 1, 64);
        u64 lastprev = (r > 0) ? __shfl(vals[r - 1], 63, 64) : 0ull;
        int idx = r * 64 + lane;
        u64 prev = (lane == 0) ? lastprev : pv;
        if (idx < (int)cnt) {
          keys[s + idx] = vals[r];
          bool flag = (idx == 0) || ((vals[r] >> OB) != (prev >> OB));
          u32 mx = (u32)((vals[r] >> OB) & smask);
          cfe[s + idx] = (flag && ((ov + (int)occm[mx]) == 1)) ? 1u : 0u;
        }
      }
    } else if (lane == 0) {
      for (u32 i = s + 1; i < e; i++) {
        u64 kk = keys[i]; u32 j = i;
        while (j > s && keys[j - 1] > kk) { keys[j] = keys[j - 1]; j--; }
        keys[j] = kk;
      }
      for (u32 j = s; j < e; j++) {
        bool flag = (j == s) || ((keys[j] >> OB) != (keys[j - 1] >> OB));
        u32 mx = (u32)((keys[j] >> OB) & smask);
        cfe[j] = (flag && ((ov + (int)occm[mx]) == 1)) ? 1u : 0u;
      }
    }
  }
}

// sliced sweep over sorted keys: idx_map[occ] = crossing-rank or -1; emit ie list
__global__ void k_idxscatter8(const u64* keys, const u32* S, const unsigned char* occm,
                              int* idx_map, u64* ie, const u32* hdr, int SB, int OB) {
  u32 E = hdr[1];
  int g = blockIdx.x & 7;
  u64 omask = ((u64)1 << OB) - 1;
  u64 smask = ((u64)1 << SB) - 1;
  for (long long i = (long long)(blockIdx.x >> 3) * blockDim.x + threadIdx.x; i < (long long)E;
       i += (long long)(gridDim.x >> 3) * blockDim.x) {
    u64 k = keys[i];
    u32 oidx = (u32)(k & omask);
    u32 mx = (u32)((k >> OB) & smask);
    u32 mn = (u32)(k >> (SB + OB));
    bool flag = (i == 0) || ((k >> OB) != (keys[i - 1] >> OB));
    bool cf = ((int)occm[mn] + (int)occm[mx]) == 1;
    u32 sv = S[i];
    int mapval = cf ? (int)(flag ? sv : sv - 1u) : -1;
    u32 slice = (u32)(((u64)oidx * 8ull) / (u64)E);
    if (slice == (u32)g) idx_map[oidx] = mapval;
    if (g == 0 && flag && cf) ie[sv] = ((u64)mn << 32) | (u64)mx;
  }
}

__global__ void k_interp(const u64* ie, const float* pos, const float* sdf,
                         const float* th, float* out, const u32* hdr) {
  u32 EC = hdr[3];
  float t = th[0];
  GSLOOP(m, EC) {
    u64 k = ie[m]; int a = (int)(k >> 32), b = (int)(k & 0xffffffffu);
    float s0 = sdf[a], s1 = sdf[b];
    if (s0 > 0.f && s1 > 0.f) { s0 = __fsub_rn(s0, t); s1 = __fsub_rn(s1, t); }
    float denom = __fadd_rn(s0, -s1);
    float w0 = __fdiv_rn(-s1, denom);
    float w1 = __fdiv_rn(s0, denom);
    long long base = 3ll * m;
    #pragma unroll
    for (int kk = 0; kk < 3; kk++)
      out[base + kk] = __fadd_rn(__fmul_rn(pos[3ll*a + kk], w0), __fmul_rn(pos[3ll*b + kk], w1));
  }
}

__global__ void k_pred_faces(const unsigned char* ti, u32* S1, u32* S2, long long F) {
  GSLOOP(f, F) {
    int b = ti[f]; bool valid = (b != 0 && b != 15); int nt = c_NTRI[b];
    S1[f] = (valid && nt == 1) ? 1u : 0u;
    S2[f] = (valid && nt == 2) ? 1u : 0u;
  }
}

__global__ void k_faces(const u32* vidx, const unsigned char* ti, const int* idx_map,
                        const u32* S1, const u32* S2, float* out, const u32* hdr) {
  u32 V = hdr[0];
  unsigned long long fo = 3ull * hdr[3];
  u32 Nf1 = hdr[4];
  GSLOOP(t, V) {
    u32 f = vidx[t]; int b = ti[f]; int nt = c_NTRI[b];
    if (nt == 1) {
      unsigned long long base = fo + 3ull * S1[f];
      for (int k = 0; k < 3; k++) out[base + k] = (float)idx_map[6*t + c_TRI[b][k]];
    } else {
      unsigned long long base = fo + 3ull * Nf1 + 6ull * S2[f];
      for (int k = 0; k < 6; k++) out[base + k] = (float)idx_map[6*t + c_TRI[b][k]];
    }
  }
}

__global__ void k_pred_tets(const unsigned char* ti, u32* S1, u32* S2, u32* S3, long long F) {
  GSLOOP(f, F) {
    int b = ti[f]; bool valid = (b != 0 && b != 15); int ntt = c_NTET[b];
    S1[f] = (valid && ntt == 1) ? 1u : 0u;
    S2[f] = (valid && ntt == 3) ? 1u : 0u;
    S3[f] = (b == 15) ? 1u : 0u;
  }
}

__global__ void k_tets_valid(const int* tet, const u32* vidx, const unsigned char* ti,
                             const int* idx_map, const u32* S1, const u32* S2,
                             int* at, const u32* hdr, int N) {
  u32 V = hdr[0]; u32 Nt1 = hdr[6];
  GSLOOP(t, V) {
    u32 f = vidx[t]; int b = ti[f];
    int tv[10];
    for (int k = 0; k < 4; k++) tv[k] = tet[4ll*f + k];
    for (int j = 0; j < 6; j++) tv[4 + j] = idx_map[6*t + j] + N;
    int ntt = c_NTET[b];
    if (ntt == 1) {
      long long base = 4ll * S1[f];
      for (int k = 0; k < 4; k++) at[base + k] = tv[c_TET[b][k]];
    } else {
      long long base = 4ll * Nt1 + 12ll * S2[f];
      for (int k = 0; k < 12; k++) at[base + k] = tv[c_TET[b][k]];
    }
  }
}

__global__ void k_tets_inner(const int* tet, const unsigned char* ti, const u32* S3,
                             int* at, const u32* hdr, long long F) {
  long long base0 = 4ll * hdr[6] + 12ll * hdr[7];
  GSLOOP(f, F) {
    if (ti[f] == 15) {
      long long base = base0 + 4ll * S3[f];
      for (int k = 0; k < 4; k++) at[base + k] = tet[4*f + k];
    }
  }
}

__global__ void k_mark(const int* at, u32* Big, const u32* hdr) {
  long long NA = 4ll * hdr[6] + 12ll * hdr[7] + 4ll * hdr[8];
  GSLOOP(i, NA) Big[at[i]] = 1u;
}

__global__ void k_vtm(const u32* Big, const float* pos, float* out, const u32* hdr, int N) {
  u32 R = hdr[10], NU = hdr[9];
  unsigned long long vtm = 3ull * hdr[3] + 3ull * (hdr[4] + 2u * hdr[5]);
  GSLOOP(v, R) {
    u32 r = Big[v];
    u32 nx = (v + 1 < (long long)R) ? Big[v + 1] : NU;
    if (nx > r) {
      unsigned long long base = vtm + 3ull * r;
      if (v < N) { for (int k = 0; k < 3; k++) out[base + k] = pos[3*v + k]; }
      else { long long src = 3ll * (v - N); for (int k = 0; k < 3; k++) out[base + k] = out[src + k]; }
    }
  }
}

__global__ void k_tets_out(const int* at, const u32* Big, float* out, const u32* hdr) {
  long long NA = 4ll * hdr[6] + 12ll * hdr[7] + 4ll * hdr[8];
  unsigned long long toff = 3ull * hdr[3] + 3ull * (hdr[4] + 2u * hdr[5]) + 3ull * hdr[9];
  GSLOOP(i, NA) out[toff + i] = (float)Big[at[i]];
}

// ---------------- host ----------------
extern "C" void kernel_launch(void* const* d_in, const int* in_sizes, int n_in,
                              void* d_out, int out_size, void* d_ws, size_t ws_size,
                              hipStream_t stream) {
  const float* pos = (const float*)d_in[0];
  const float* sdf = (const float*)d_in[1];
  const int*   tet = (const int*)d_in[2];
  const float* th  = (const float*)d_in[3];
  float* out = (float*)d_out;

  const int N = in_sizes[1];
  const long long F = (long long)in_sizes[2] / 4;
  const long long MAXE = 6 * F;
  const long long RMAX = (long long)N + MAXE;
  (void)n_in; (void)out_size; (void)ws_size;

  // key layout: [mn:SB | mx:SB | occurrence:OB], must fit 64 bits
  int SB = 1; while ((1ll << SB) < (long long)N) SB++;
  int OB = 1; while ((1ll << OB) < MAXE) OB++;

  char* w = (char*)d_ws;
  size_t off = 0;
  auto alloc = [&](size_t b) -> char* {
    char* p = w + off; off = (off + b + 255) & ~(size_t)255; return p;
  };
  u32* hdr            = (u32*)alloc(64 * 4);
  unsigned char* occ  = (unsigned char*)alloc((size_t)N);
  unsigned char* tiA  = (unsigned char*)alloc((size_t)F);
  u32* S1             = (u32*)alloc(4 * (size_t)F);
  u32* S2             = (u32*)alloc(4 * (size_t)F);
  u32* S3             = (u32*)alloc(4 * (size_t)F);
  u32* vidx           = (u32*)alloc(4 * (size_t)F);
  u32* hist           = (u32*)alloc(4 * ((size_t)N + 2));
  u32* cursor         = (u32*)alloc(4 * ((size_t)N + 2));
  // keys region (8*MAXE); later reused as all_tets (12F ints = 48MB)
  char* big_mem       = alloc(8 * (size_t)MAXE);
  u64* keys = (u64*)big_mem; int* at = (int*)big_mem;
  u64* ie             = (u64*)alloc(8 * (size_t)MAXE);
  u32* Big            = (u32*)alloc(4 * ((size_t)RMAX + 2));
  u32* cfe            = (u32*)alloc(4 * (size_t)MAXE);
  int* idx_map        = (int*)alloc(4 * (size_t)MAXE);
  u32* partials       = (u32*)alloc(4 * 8192);

  const int GRID = 4096, BLK = 256;
  auto scan = [&](u32* data, int nslot, u32 nmax, int tslot) {
    int nb = (int)((nmax + 2047u) / 2048u);
    k_scan1<<<nb, 256, 0, stream>>>(data, partials, hdr, nslot, nmax);
    k_scan2<<<1, 1024, 0, stream>>>(partials, hdr, nslot, nmax, hdr, tslot);
    k_scan3<<<nb, 256, 0, stream>>>(data, partials, hdr, nslot, nmax);
  };

  k_zero32<<<1, 64, 0, stream>>>(hdr, 64);
  k_zero32<<<2048, BLK, 0, stream>>>(hist, (long long)N + 2);

  k_occ<<<GRID, BLK, 0, stream>>>(sdf, th, occ, N);
  k_ti<<<GRID, BLK, 0, stream>>>(tet, occ, tiA, S1, F);
  scan(S1, -1, (u32)F, 0);                                   // hdr[0] = V
  k_compact_valid<<<GRID, BLK, 0, stream>>>(S1, tiA, vidx, F);

  k_hist<<<GRID, BLK, 0, stream>>>(tet, vidx, hdr, hist);
  scan(hist, -1, (u32)(N + 1), 1);                           // hdr[1] = E; hist -> off
  k_bnd<<<1, 64, 0, stream>>>(hist, hdr, N);                 // hdr[16..24] octile bounds
  k_copy32<<<GRID, BLK, 0, stream>>>(hist, cursor, (long long)N + 2);
  k_scatter8<<<GRID, BLK, 0, stream>>>(tet, vidx, hdr, cursor, keys, SB, OB);
  k_bsort<<<GRID, BLK, 0, stream>>>(hist, keys, cfe, occ, N, SB, OB);

  scan(cfe, 1, (u32)MAXE, 3);                                // hdr[3] = Ecross; cfe -> S
  k_setr<<<1, 1, 0, stream>>>(hdr, N);                       // hdr[10] = R = N + Ecross
  k_idxscatter8<<<GRID, BLK, 0, stream>>>(keys, cfe, occ, idx_map, ie, hdr, SB, OB);

  k_interp<<<GRID, BLK, 0, stream>>>(ie, pos, sdf, th, out, hdr);

  k_pred_faces<<<GRID, BLK, 0, stream>>>(tiA, S1, S2, F);
  scan(S1, -1, (u32)F, 4);                                   // hdr[4] = Nf1
  scan(S2, -1, (u32)F, 5);                                   // hdr[5] = Nf2
  k_faces<<<GRID, BLK, 0, stream>>>(vidx, tiA, idx_map, S1, S2, out, hdr);

  k_pred_tets<<<GRID, BLK, 0, stream>>>(tiA, S1, S2, S3, F);
  scan(S1, -1, (u32)F, 6);                                   // hdr[6] = Nt1
  scan(S2, -1, (u32)F, 7);                                   // hdr[7] = Nt3
  scan(S3, -1, (u32)F, 8);                                   // hdr[8] = Ninner
  k_tets_valid<<<GRID, BLK, 0, stream>>>(tet, vidx, tiA, idx_map, S1, S2, at, hdr, N);
  k_tets_inner<<<GRID, BLK, 0, stream>>>(tet, tiA, S3, at, hdr, F);

  k_zero_hdr<<<GRID, BLK, 0, stream>>>(Big, hdr, 10, 2u);
  k_mark<<<GRID, BLK, 0, stream>>>(at, Big, hdr);
  scan(Big, 10, (u32)RMAX, 9);                               // hdr[9] = NU
  k_vtm<<<GRID, BLK, 0, stream>>>(Big, pos, out, hdr, N);
  k_tets_out<<<GRID, BLK, 0, stream>>>(at, Big, out, hdr);
}